// Round 2
// baseline (265.851 us; speedup 1.0000x reference)
//
#include <hip/hip_runtime.h>

#define BATCH 16
#define CH    16
#define HH    128
#define WW    128
#define NC    8            // n_convs
#define TR    16           // rows per band
#define HR    (TR + 2)     // 18 halo rows
#define FW    (WW + 2)     // 130 halo cols

// Per-element features: f0=silu(v), f1=tanh(v), f2=2t^2 (=T2+1), f3=T3=4t^3-3t.
// bias_j = sum_i (W0 - W2)[j,i] absorbs T0 and the +1 shift of f2, so features
// are exactly (0,0,0,0) at v=0 -> zero padding handled by computing feat(0).
__global__ __launch_bounds__(256, 4)
void kan_conv_kernel(const float* __restrict__ x,
                     const float* __restrict__ cheby,   // (8,9,4)
                     const float* __restrict__ bwt,     // (8,9)
                     const float* __restrict__ scl,     // (8,9)
                     float* __restrict__ out)           // (16,128,128,128)
{
    __shared__ float4 feat[HR][FW];      // 37,440 B
    __shared__ float4 wgt[9 * NC];       // [tap*8 + j] = (bw, W1, W2, W3)
    __shared__ float  bias[NC];

    const int tid  = threadIdx.x;        // 0..255
    const int band = blockIdx.x * TR;    // 0,16,...,112
    const int bz   = blockIdx.y;         // plane = b*CH + c

    // ---- stage combined weights ----
    if (tid < 9 * NC) {
        int j = tid / 9, i = tid % 9;
        float s  = scl[j * 9 + i];
        float w1 = cheby[(j * 9 + i) * 4 + 1] * s;
        float w2 = cheby[(j * 9 + i) * 4 + 2] * s;
        float w3 = cheby[(j * 9 + i) * 4 + 3] * s;
        wgt[i * NC + j] = make_float4(bwt[j * 9 + i], w1, w2, w3);
    } else if (tid >= 128 && tid < 128 + NC) {
        int j = tid - 128;
        float b = 0.f;
        #pragma unroll
        for (int i = 0; i < 9; ++i)
            b += (cheby[(j * 9 + i) * 4 + 0] - cheby[(j * 9 + i) * 4 + 2]) * scl[j * 9 + i];
        bias[j] = b;
    }

    // ---- stage halo band, compute features (coalesced float4 x loads) ----
    const float* xp = x + (size_t)bz * HH * WW;
    for (int idx = tid; idx < HR * (WW / 4); idx += 256) {
        int row = idx >> 5;              // /32
        int cg  = idx & 31;
        int gh  = band + row - 1;
        float4 v = make_float4(0.f, 0.f, 0.f, 0.f);
        if ((unsigned)gh < (unsigned)HH)
            v = ((const float4*)(xp + gh * WW))[cg];
        float vv[4] = {v.x, v.y, v.z, v.w};
        #pragma unroll
        for (int k = 0; k < 4; ++k) {
            float val = vv[k];
            float e1 = __expf(val);
            float e2 = __expf(2.f * val);
            float sg = 1.f - __builtin_amdgcn_rcpf(1.f + e1);     // sigmoid
            float t  = 1.f - 2.f * __builtin_amdgcn_rcpf(e2 + 1.f); // tanh
            float f2 = 2.f * t * t;                                // T2 + 1
            float f3 = 2.f * t * (f2 - 1.f) - t;                   // T3
            feat[row][1 + cg * 4 + k] = make_float4(val * sg, t, f2, f3);
        }
    }
    if (tid < HR) {                      // zero halo columns (x = -1 and 128)
        feat[tid][0]      = make_float4(0.f, 0.f, 0.f, 0.f);
        feat[tid][FW - 1] = make_float4(0.f, 0.f, 0.f, 0.f);
    }
    __syncthreads();

    // ---- conv: thread owns col c, rows r0+2s (s=0..7); full tap unroll ----
    const int c  = tid & 127;            // 0..127
    const int r0 = tid >> 7;             // 0..1

    float acc[8][NC];
    #pragma unroll
    for (int s = 0; s < 8; ++s)
        #pragma unroll
        for (int j = 0; j < NC; ++j)
            acc[s][j] = bias[j];

    #pragma unroll
    for (int i = 0; i < 9; ++i) {
        const int dr = i / 3, dc = i % 3;        // compile-time after unroll
        float4 f[8];
        #pragma unroll
        for (int s = 0; s < 8; ++s)
            f[s] = feat[r0 + 2 * s + dr][c + dc]; // 16B/lane stride: canonical
        #pragma unroll
        for (int j = 0; j < NC; ++j) {
            float4 w = wgt[i * NC + j];           // wave-uniform broadcast
            #pragma unroll
            for (int s = 0; s < 8; ++s) {
                acc[s][j] += w.x * f[s].x;
                acc[s][j] += w.y * f[s].y;
                acc[s][j] += w.z * f[s].z;
                acc[s][j] += w.w * f[s].w;
            }
        }
    }

    // ---- store: 64 consecutive floats per wave-store (256B contiguous) ----
    float* op = out + (size_t)(bz * NC) * HH * WW + (band + r0) * WW + c;
    #pragma unroll
    for (int j = 0; j < NC; ++j)
        #pragma unroll
        for (int s = 0; s < 8; ++s)
            op[(size_t)j * HH * WW + s * 2 * WW] = acc[s][j];
}

extern "C" void kernel_launch(void* const* d_in, const int* in_sizes, int n_in,
                              void* d_out, int out_size, void* d_ws, size_t ws_size,
                              hipStream_t stream) {
    const float* x     = (const float*)d_in[0];
    const float* cheby = (const float*)d_in[1];
    const float* bwt   = (const float*)d_in[2];
    const float* scl   = (const float*)d_in[3];
    float* out = (float*)d_out;

    dim3 grid(HH / TR, BATCH * CH);      // 8 x 256 = 2048 blocks
    dim3 block(256);
    hipLaunchKernelGGL(kan_conv_kernel, grid, block, 0, stream, x, cheby, bwt, scl, out);
}

// Round 3
// 168.624 us; speedup vs baseline: 1.5766x; 1.5766x over previous
//
#include <hip/hip_runtime.h>

#define BATCH 16
#define CH    16
#define HH    128
#define WW    128
#define NC    8            // n_convs
#define TR    8            // output rows per band
#define HR    (TR + 2)     // 10 halo rows
#define FW    (WW + 2)     // 130 halo cols

// Per-element features: f0=silu(v), f1=tanh(v), f2=2t^2 (=T2+1), f3=T3=4t^3-3t.
// bias_j = sum_i (W0 - W2)[j,i] absorbs T0 and the +1 shift of f2, so features
// are exactly (0,0,0,0) at v=0 -> zero padding handled by feat(0)=0.
// Register budget is the whole game here (round 2 spilled): acc[4][8]=32 VGPRs.
__global__ __launch_bounds__(256, 4)
void kan_conv_kernel(const float* __restrict__ x,
                     const float* __restrict__ cheby,   // (8,9,4)
                     const float* __restrict__ bwt,     // (8,9)
                     const float* __restrict__ scl,     // (8,9)
                     float* __restrict__ out)           // (16,128,128,128)
{
    __shared__ float4 feat[HR][FW];      // 20,800 B
    __shared__ float4 wgt[9 * NC];       // [tap*8 + j] = (bw, W1, W2, W3)
    __shared__ float  bias[NC];

    const int tid  = threadIdx.x;        // 0..255
    const int band = blockIdx.x * TR;
    const int bz   = blockIdx.y;         // plane = b*CH + c

    // ---- stage combined weights ----
    if (tid < 9 * NC) {
        int j = tid / 9, i = tid % 9;
        float s = scl[j * 9 + i];
        wgt[i * NC + j] = make_float4(bwt[j * 9 + i],
                                      cheby[(j * 9 + i) * 4 + 1] * s,
                                      cheby[(j * 9 + i) * 4 + 2] * s,
                                      cheby[(j * 9 + i) * 4 + 3] * s);
    } else if (tid >= 128 && tid < 128 + NC) {
        int j = tid - 128;
        float b = 0.f;
        #pragma unroll
        for (int i = 0; i < 9; ++i)
            b += (cheby[(j * 9 + i) * 4 + 0] - cheby[(j * 9 + i) * 4 + 2]) * scl[j * 9 + i];
        bias[j] = b;
    }

    // ---- stage halo band: one element per thread, lane-consecutive cols ----
    // write stride = 16 B/lane -> canonical conflict-free b128 LDS pattern
    const float* xp = x + (size_t)bz * HH * WW;
    for (int idx = tid; idx < HR * FW; idx += 256) {
        int row = idx / FW;
        int col = idx - row * FW;
        int gh  = band + row - 1;
        int gw  = col - 1;
        float v = 0.f;
        if ((unsigned)gh < (unsigned)HH && (unsigned)gw < (unsigned)WW)
            v = xp[gh * WW + gw];                         // 4B/lane coalesced
        float e1 = __expf(v);
        float e2 = e1 * e1;                               // exp(2v)
        float sg = 1.f - __builtin_amdgcn_rcpf(1.f + e1); // sigmoid(v)
        float t  = 1.f - 2.f * __builtin_amdgcn_rcpf(e2 + 1.f); // tanh(v)
        float f2 = 2.f * t * t;                           // T2 + 1
        float f3 = 2.f * t * (f2 - 1.f) - t;              // T3
        feat[row][col] = make_float4(v * sg, t, f2, f3);
    }
    __syncthreads();

    // ---- conv: thread owns col c, rows r0+2s (s=0..3); taps fully unrolled ----
    const int c  = tid & 127;            // 0..127
    const int r0 = tid >> 7;             // 0..1

    float acc[4][NC];                    // 32 VGPRs — fits, no spill
    #pragma unroll
    for (int s = 0; s < 4; ++s)
        #pragma unroll
        for (int j = 0; j < NC; ++j)
            acc[s][j] = bias[j];

    #pragma unroll
    for (int dr = 0; dr < 3; ++dr) {
        #pragma unroll
        for (int dc = 0; dc < 3; ++dc) {
            float4 f[4];
            #pragma unroll
            for (int s = 0; s < 4; ++s)
                f[s] = feat[r0 + 2 * s + dr][c + dc];   // 16B/lane: conflict-free
            #pragma unroll
            for (int j = 0; j < NC; ++j) {
                float4 w = wgt[(dr * 3 + dc) * NC + j]; // uniform broadcast
                #pragma unroll
                for (int s = 0; s < 4; ++s) {
                    acc[s][j] += w.x * f[s].x;
                    acc[s][j] += w.y * f[s].y;
                    acc[s][j] += w.z * f[s].z;
                    acc[s][j] += w.w * f[s].w;
                }
            }
        }
    }

    // ---- store: each wave writes 64 consecutive floats (256B contiguous) ----
    float* op = out + (size_t)(bz * NC) * HH * WW + (size_t)(band + r0) * WW + c;
    #pragma unroll
    for (int j = 0; j < NC; ++j)
        #pragma unroll
        for (int s = 0; s < 4; ++s)
            op[(size_t)j * HH * WW + s * 2 * WW] = acc[s][j];
}

extern "C" void kernel_launch(void* const* d_in, const int* in_sizes, int n_in,
                              void* d_out, int out_size, void* d_ws, size_t ws_size,
                              hipStream_t stream) {
    const float* x     = (const float*)d_in[0];
    const float* cheby = (const float*)d_in[1];
    const float* bwt   = (const float*)d_in[2];
    const float* scl   = (const float*)d_in[3];
    float* out = (float*)d_out;

    dim3 grid(HH / TR, BATCH * CH);      // 16 x 256 = 4096 blocks
    dim3 block(256);
    hipLaunchKernelGGL(kan_conv_kernel, grid, block, 0, stream, x, cheby, bwt, scl, out);
}